// Round 13
// baseline (679.635 us; speedup 1.0000x reference)
//
#include <hip/hip_runtime.h>
#include <hip/hip_bf16.h>

#define HEADS 4
#define NEG 0.2f
#define LN_EPS 1e-5f
#define LOG2E 1.4426950408889634f

typedef unsigned int u32;
typedef unsigned short u16;

typedef __attribute__((ext_vector_type(8))) short bf16x8;
typedef __attribute__((ext_vector_type(4))) float f32x4;

__device__ __forceinline__ float bflo(u32 u) { return __uint_as_float(u << 16); }
__device__ __forceinline__ float bfhi(u32 u) { return __uint_as_float(u & 0xffff0000u); }
__device__ __forceinline__ u16 f2bf(float f) {
    u32 u = __float_as_uint(f);
    u32 r = u + 0x7fffu + ((u >> 16) & 1u);
    return (u16)(r >> 16);
}

template <int CTRL>
__device__ __forceinline__ float dppadd(float e) {
    float t = __int_as_float(
        __builtin_amdgcn_update_dpp(0, __float_as_int(e), CTRL, 0xf, 0xf, false));
    return e + t;
}
// sum over each 8-lane group
__device__ __forceinline__ float redsum8(float e) {
    e = dppadd<0xB1>(e);   // quad_perm [1,0,3,2]
    e = dppadd<0x4E>(e);   // quad_perm [2,3,0,1]
    e = dppadd<0x141>(e);  // row_half_mirror
    return e;
}

#define BSH 9
#define BSZ 512
#define NSUB 8

// ---------------- CSR build (XCD-affine substreamed buckets) ----------------
__global__ void k_init(int* bcur, int ncur, float* buckets, int* col_src, int E2) {
    int i = blockIdx.x * blockDim.x + threadIdx.x;
    if (i < ncur) bcur[i] = 0;
    if (i < 1024) buckets[i] = 0.f;
    if (i < 8) col_src[E2 + i] = 0;  // sentinel pad: clamp-free prefetch
}

// partition edges into dst-buckets; substream = blockIdx&7 (~XCD id). Record
// packed: src | dstLocal<<20  (requires n < 2^20).
__global__ void k_bucketA(const int* __restrict__ src, const int* __restrict__ dst,
                          int* __restrict__ bcur, u32* __restrict__ stage,
                          int E, int subcap) {
    int sub = blockIdx.x & (NSUB - 1);
    int stride = gridDim.x * blockDim.x;
    for (int e = blockIdx.x * blockDim.x + threadIdx.x; e < E; e += stride) {
        int s = src[e], d = dst[e];
        int b = d >> BSH;
        int st = b * NSUB + sub;
        int pos = atomicAdd(&bcur[st * 16], 1);
        if (pos < subcap)
            stage[(size_t)st * subcap + pos] = (u32)s | ((u32)(d & (BSZ - 1)) << 20);
    }
}

// per-bucket LDS histogram -> per-node counts (incl. self loop)
__global__ void k_bcount(const int* __restrict__ bcur, const u32* __restrict__ stage,
                         int* __restrict__ cnt, int n, int subcap) {
    __shared__ int hist[BSZ];
    int b = blockIdx.x;
    int base = b << BSH;
    for (int i = threadIdx.x; i < BSZ; i += 256) hist[i] = 1;  // self loop
    __syncthreads();
    for (int ss = 0; ss < NSUB; ++ss) {
        int st = b * NSUB + ss;
        int c = min(bcur[st * 16], subcap);
        const u32* sp = stage + (size_t)st * subcap;
        for (int i = threadIdx.x; i < c; i += 256)
            atomicAdd(&hist[(sp[i] >> 20) & (BSZ - 1)], 1);
    }
    __syncthreads();
    for (int i = threadIdx.x; i < BSZ; i += 256)
        if (base + i < n) cnt[base + i] = hist[i];
}

__global__ void k_blocksum(const int* __restrict__ cnt, int* bsum, int n) {
    __shared__ int sh[256];
    int i = blockIdx.x * 256 + threadIdx.x;
    int v = (i < n) ? cnt[i] : 0;
    sh[threadIdx.x] = v;
    __syncthreads();
    for (int off = 128; off; off >>= 1) {
        if (threadIdx.x < off) sh[threadIdx.x] += sh[threadIdx.x + off];
        __syncthreads();
    }
    if (threadIdx.x == 0) bsum[blockIdx.x] = sh[0];
}

__global__ void k_scan_bsum(const int* __restrict__ bsum, int* boff, int nb) {
    __shared__ int sh[1024];
    int t = threadIdx.x;
    int v = (t < nb) ? bsum[t] : 0;
    sh[t] = v;
    __syncthreads();
    for (int off = 1; off < 1024; off <<= 1) {
        int a = (t >= off) ? sh[t - off] : 0;
        __syncthreads();
        sh[t] += a;
        __syncthreads();
    }
    if (t < nb) boff[t] = sh[t] - v;  // exclusive
}

__global__ void k_make_ptr(const int* cnt, const int* __restrict__ boff,
                           int* rowptr, int n) {
    __shared__ int sh[256];
    int t = threadIdx.x;
    int i = blockIdx.x * 256 + t;
    int v = (i < n) ? cnt[i] : 0;
    sh[t] = v;
    __syncthreads();
    for (int off = 1; off < 256; off <<= 1) {
        int a = (t >= off) ? sh[t - off] : 0;
        __syncthreads();
        sh[t] += a;
        __syncthreads();
    }
    int incl = sh[t] + boff[blockIdx.x];
    if (i < n) rowptr[i + 1] = incl;
    if (i == 0) rowptr[0] = 0;
}

// per-bucket scatter via LDS cursors
__global__ void k_bfill(const int* __restrict__ bcur, const u32* __restrict__ stage,
                        const int* __restrict__ rowptr, int* __restrict__ col_src,
                        int n, int subcap) {
    __shared__ int lcur[BSZ];
    int b = blockIdx.x;
    int base = b << BSH;
    for (int i = threadIdx.x; i < BSZ; i += 256) {
        if (base + i < n) {
            int rp = rowptr[base + i];
            col_src[rp] = base + i;  // self loop first (order only affects fp rounding)
            lcur[i] = rp + 1;
        }
    }
    __syncthreads();
    for (int ss = 0; ss < NSUB; ++ss) {
        int st = b * NSUB + ss;
        int c = min(bcur[st * 16], subcap);
        const u32* sp = stage + (size_t)st * subcap;
        for (int i = threadIdx.x; i < c; i += 256) {
            u32 rec = sp[i];
            int p = atomicAdd(&lcur[(rec >> 20) & (BSZ - 1)], 1);
            col_src[p] = (int)(rec & 0xFFFFFu);
        }
    }
}

// ---------------- W -> bf16 MFMA-fragment layout ----------------
__global__ void k_prep_w(const float* __restrict__ Wl, const float* __restrict__ Wr,
                         u16* __restrict__ wt) {
    int idx = blockIdx.x * 256 + threadIdx.x;
    if (idx >= 6 * 16384) return;
    int mat = idx >> 14;
    int rem = idx & 16383;
    int t = rem >> 10;
    int kq = (rem >> 8) & 3;
    int nn = (rem >> 4) & 15;
    int half = (rem >> 3) & 1;
    int j = rem & 7;
    int c = t * 16 + nn;
    int k = kq * 8 + half * 32 + j;
    const float* W = (mat < 3) ? (Wl + (size_t)mat * 16384) : (Wr + (size_t)(mat - 3) * 16384);
    wt[idx] = f2bf(W[k * 256 + c]);
}

// ---------------- MFMA GEMM, 256 rows/block: amortizes wt fragment reads 4x ----------------
__global__ __launch_bounds__(256) void k_gemm_mfma(
        const float* __restrict__ x, const u16* __restrict__ wtl,
        const u16* __restrict__ wtr, u16* __restrict__ xl, u16* __restrict__ xr, int n,
        const float* __restrict__ musig, const float* __restrict__ lnw,
        const float* __restrict__ lnb, int useln) {
    int w = threadIdx.x >> 6;
    int lane = threadIdx.x & 63;
    int rbase = blockIdx.x * 256 + w * 64;
    int rloc = lane & 15;
    int c0 = (lane >> 4) * 8;

    float mu = 0.f, rs = 1.f;
    if (useln) { mu = musig[0]; rs = musig[1]; }

    bf16x8 fa0[4], fa1[4];
#pragma unroll
    for (int g = 0; g < 4; ++g) {
        int r = rbase + g * 16 + rloc;
        float av[16];
        if (r < n) {
            const float* xp = x + (size_t)r * 64;
            float4 t0 = *(const float4*)(xp + c0);
            float4 t1 = *(const float4*)(xp + c0 + 4);
            float4 t2 = *(const float4*)(xp + c0 + 32);
            float4 t3 = *(const float4*)(xp + c0 + 36);
            av[0] = t0.x; av[1] = t0.y; av[2] = t0.z; av[3] = t0.w;
            av[4] = t1.x; av[5] = t1.y; av[6] = t1.z; av[7] = t1.w;
            av[8] = t2.x; av[9] = t2.y; av[10] = t2.z; av[11] = t2.w;
            av[12] = t3.x; av[13] = t3.y; av[14] = t3.z; av[15] = t3.w;
            if (useln) {
                float4 w0 = *(const float4*)(lnw + c0);
                float4 w1 = *(const float4*)(lnw + c0 + 4);
                float4 w2 = *(const float4*)(lnw + c0 + 32);
                float4 w3 = *(const float4*)(lnw + c0 + 36);
                float4 b0 = *(const float4*)(lnb + c0);
                float4 b1 = *(const float4*)(lnb + c0 + 4);
                float4 b2 = *(const float4*)(lnb + c0 + 32);
                float4 b3 = *(const float4*)(lnb + c0 + 36);
                float lw[16] = {w0.x,w0.y,w0.z,w0.w, w1.x,w1.y,w1.z,w1.w,
                                w2.x,w2.y,w2.z,w2.w, w3.x,w3.y,w3.z,w3.w};
                float lb[16] = {b0.x,b0.y,b0.z,b0.w, b1.x,b1.y,b1.z,b1.w,
                                b2.x,b2.y,b2.z,b2.w, b3.x,b3.y,b3.z,b3.w};
#pragma unroll
                for (int j = 0; j < 16; ++j) av[j] = (av[j] - mu) * rs * lw[j] + lb[j];
            }
        } else {
#pragma unroll
            for (int j = 0; j < 16; ++j) av[j] = 0.f;
        }
#pragma unroll
        for (int j = 0; j < 8; ++j) {
            fa0[g][j] = (short)f2bf(av[j]);
            fa1[g][j] = (short)f2bf(av[8 + j]);
        }
    }

    int nn = lane & 15;
    int kq = lane >> 4;
    int fragoff = kq * 256 + nn * 16;

#pragma unroll 2
    for (int t = 0; t < 16; ++t) {
        const u16* wp = wtl + t * 1024 + fragoff;
        bf16x8 fb0 = *(const bf16x8*)(wp);
        bf16x8 fb1 = *(const bf16x8*)(wp + 8);
        int cb = t * 16;
#pragma unroll
        for (int g = 0; g < 4; ++g) {
            f32x4 acc = {0.f, 0.f, 0.f, 0.f};
            acc = __builtin_amdgcn_mfma_f32_16x16x32_bf16(fa0[g], fb0, acc, 0, 0, 0);
            acc = __builtin_amdgcn_mfma_f32_16x16x32_bf16(fa1[g], fb1, acc, 0, 0, 0);
            int row0 = rbase + g * 16 + kq * 4;
#pragma unroll
            for (int reg = 0; reg < 4; ++reg) {
                int R = row0 + reg;
                if (R < n) xl[(size_t)R * 256 + cb + nn] = f2bf(acc[reg]);
            }
        }
    }
#pragma unroll 2
    for (int t = 0; t < 16; ++t) {
        const u16* wp = wtr + t * 1024 + fragoff;
        bf16x8 fb0 = *(const bf16x8*)(wp);
        bf16x8 fb1 = *(const bf16x8*)(wp + 8);
        int cb = t * 16;
#pragma unroll
        for (int g = 0; g < 4; ++g) {
            f32x4 acc = {0.f, 0.f, 0.f, 0.f};
            acc = __builtin_amdgcn_mfma_f32_16x16x32_bf16(fa0[g], fb0, acc, 0, 0, 0);
            acc = __builtin_amdgcn_mfma_f32_16x16x32_bf16(fa1[g], fb1, acc, 0, 0, 0);
            int row0 = rbase + g * 16 + kq * 4;
#pragma unroll
            for (int reg = 0; reg < 4; ++reg) {
                int R = row0 + reg;
                if (R < n) xr[(size_t)R * 256 + cb + nn] = f2bf(acc[reg]);
            }
        }
    }
}

// ---------------- Fused GATv2 edge pass ----------------
// Wave per dst node; half = lane>>5 (edge stream), l32 = lane&31, 8 ch/lane,
// head = l32>>3. Prefetch depth 2 per stream (2 gathers in flight/lane).
// Logit: 0.6*lrelu(u) = 0.6*(u + (2/3)|u|) -> 2 VOP3/channel, abs is a free
// input modifier, no extra VGPRs. exp2 softmax, fused LN stats.
__global__ __launch_bounds__(256) void k_fused(
        const u16* __restrict__ xl, const u16* __restrict__ xr,
        const int* __restrict__ rowptr, const int* __restrict__ col_src,
        const float* __restrict__ att, const float* __restrict__ bias,
        float* __restrict__ y, float* __restrict__ buckets, int n) {
    __shared__ float shv[4][HEADS][64];
    __shared__ float redS[4], redQ[4];
    int w = threadIdx.x >> 6;
    int node = blockIdx.x * 4 + w;
    int lane = threadIdx.x & 63;
    int half = lane >> 5;
    int l32 = lane & 31;
    bool act = node < n;
    float yv = 0.f;

    if (act) {
        float a[8], rr[8];
        {
            const float* ap = att + l32 * 8;
            float4 a0 = *(const float4*)(ap);
            float4 a1 = *(const float4*)(ap + 4);
            const float c6 = 0.6f * LOG2E;
            a[0] = a0.x * c6; a[1] = a0.y * c6; a[2] = a0.z * c6; a[3] = a0.w * c6;
            a[4] = a1.x * c6; a[5] = a1.y * c6; a[6] = a1.z * c6; a[7] = a1.w * c6;
            uint4 rv = *(const uint4*)(xr + (size_t)node * 256 + l32 * 8);
            rr[0] = bflo(rv.x); rr[1] = bfhi(rv.x);
            rr[2] = bflo(rv.y); rr[3] = bfhi(rv.y);
            rr[4] = bflo(rv.z); rr[5] = bfhi(rv.z);
            rr[6] = bflo(rv.w); rr[7] = bfhi(rv.w);
        }
        const float K23 = 0.66666667f;
        int start = rowptr[node], end = rowptr[node + 1];
        int d = end - start;
        int iters = (d + 1) >> 1;
        float acc[8] = {0.f, 0.f, 0.f, 0.f, 0.f, 0.f, 0.f, 0.f};
        float denom = 0.f;
        int j = start + half;
        const size_t co = (size_t)l32 * 8;
        // prefetch depth 2 (col_src padded by 8 zeros; reads past `end` are
        // in-bounds and masked by `valid`)
        uint4 va = *(const uint4*)(xl + (size_t)col_src[j] * 256 + co);
        uint4 vb = *(const uint4*)(xl + (size_t)col_src[j + 2] * 256 + co);
        for (int i = 0; i < iters; ++i) {
            uint4 vc = va;
            va = vb;
            bool valid = j < end;
            if (i + 2 < iters) {
                int sn = col_src[j + 4];
                vb = *(const uint4*)(xl + (size_t)sn * 256 + co);
            }
            float x0 = bflo(vc.x), x1 = bfhi(vc.x), x2 = bflo(vc.y), x3 = bfhi(vc.y);
            float x4 = bflo(vc.z), x5 = bfhi(vc.z), x6 = bflo(vc.w), x7 = bfhi(vc.w);
            float u0 = x0 + rr[0], u1 = x1 + rr[1], u2 = x2 + rr[2], u3 = x3 + rr[3];
            float u4 = x4 + rr[4], u5 = x5 + rr[5], u6 = x6 + rr[6], u7 = x7 + rr[7];
            u0 = fmaf(K23, __builtin_fabsf(u0), u0);
            u1 = fmaf(K23, __builtin_fabsf(u1), u1);
            u2 = fmaf(K23, __builtin_fabsf(u2), u2);
            u3 = fmaf(K23, __builtin_fabsf(u3), u3);
            u4 = fmaf(K23, __builtin_fabsf(u4), u4);
            u5 = fmaf(K23, __builtin_fabsf(u5), u5);
            u6 = fmaf(K23, __builtin_fabsf(u6), u6);
            u7 = fmaf(K23, __builtin_fabsf(u7), u7);
            float e = a[0] * u0;
            e = fmaf(a[1], u1, e);
            e = fmaf(a[2], u2, e);
            e = fmaf(a[3], u3, e);
            e = fmaf(a[4], u4, e);
            e = fmaf(a[5], u5, e);
            e = fmaf(a[6], u6, e);
            e = fmaf(a[7], u7, e);
            e = redsum8(e);
            float p = exp2f(e);
            p = valid ? p : 0.f;
            denom += p;
            acc[0] = fmaf(p, x0, acc[0]);
            acc[1] = fmaf(p, x1, acc[1]);
            acc[2] = fmaf(p, x2, acc[2]);
            acc[3] = fmaf(p, x3, acc[3]);
            acc[4] = fmaf(p, x4, acc[4]);
            acc[5] = fmaf(p, x5, acc[5]);
            acc[6] = fmaf(p, x6, acc[6]);
            acc[7] = fmaf(p, x7, acc[7]);
            j += 2;
        }
        // fold the two edge streams
#pragma unroll
        for (int q = 0; q < 8; ++q) acc[q] += __shfl_xor(acc[q], 32, 64);
        denom += __shfl_xor(denom, 32, 64);
        float invd = 0.25f / (denom + 1e-16f);
        if (half == 0) {
            int h = l32 >> 3;
            int cb = (l32 & 7) * 8;
#pragma unroll
            for (int q = 0; q < 8; ++q) shv[w][h][cb + q] = acc[q] * invd;
        }
        // same-wave DS write->read: in-order, no barrier needed
        yv = shv[w][0][lane] + shv[w][1][lane] + shv[w][2][lane] + shv[w][3][lane]
             + bias[lane];
        y[(size_t)node * 64 + lane] = yv;
    }

    // fused LN statistics
    float s1 = yv, s2 = yv * yv;
#pragma unroll
    for (int off = 32; off; off >>= 1) {
        s1 += __shfl_xor(s1, off, 64);
        s2 += __shfl_xor(s2, off, 64);
    }
    if (lane == 0) { redS[w] = act ? s1 : 0.f; redQ[w] = act ? s2 : 0.f; }
    __syncthreads();
    if (threadIdx.x == 0) {
        float bs = redS[0] + redS[1] + redS[2] + redS[3];
        float bq = redQ[0] + redQ[1] + redQ[2] + redQ[3];
        int b = blockIdx.x & 511;
        atomicAdd(&buckets[b], bs);
        atomicAdd(&buckets[512 + b], bq);
    }
}

// ---------------- LayerNorm finalize ----------------
__global__ void k_ln_final(float* __restrict__ buckets, float* musig, int n64) {
    int t = threadIdx.x;  // 512
    double s = (double)buckets[t];
    double q = (double)buckets[512 + t];
    __shared__ double shs[512], shq[512];
    shs[t] = s; shq[t] = q;
    __syncthreads();
    for (int off = 256; off; off >>= 1) {
        if (t < off) { shs[t] += shs[t + off]; shq[t] += shq[t + off]; }
        __syncthreads();
    }
    if (t == 0) {
        double mu = shs[0] / n64;
        double var = shq[0] / n64 - mu * mu;
        musig[0] = (float)mu;
        musig[1] = (float)(1.0 / sqrt(var + (double)LN_EPS));
    }
    buckets[t] = 0.f;
    buckets[512 + t] = 0.f;
}

__global__ void k_ln_apply(const float* __restrict__ y, const float* __restrict__ musig,
                           const float* __restrict__ w, const float* __restrict__ b,
                           float* __restrict__ out, int n64) {
    float mu = musig[0], rs = musig[1];
    int stride = gridDim.x * blockDim.x;
    for (int i = blockIdx.x * blockDim.x + threadIdx.x; i < n64; i += stride) {
        int c = i & 63;
        out[i] = (y[i] - mu) * rs * w[c] + b[c];
    }
}

extern "C" void kernel_launch(void* const* d_in, const int* in_sizes, int n_in,
                              void* d_out, int out_size, void* d_ws, size_t ws_size,
                              hipStream_t stream) {
    const float* x0   = (const float*)d_in[0];
    const int*   ei   = (const int*)d_in[1];
    const float* Wl   = (const float*)d_in[2];
    const float* Wr   = (const float*)d_in[3];
    const float* att  = (const float*)d_in[4];
    const float* bias = (const float*)d_in[5];
    const float* lnw  = (const float*)d_in[6];
    const float* lnb  = (const float*)d_in[7];

    const int n  = in_sizes[0] / 64;
    const int E  = in_sizes[1] / 2;
    const int* srcA = ei;
    const int* dstA = ei + E;

    const int NBUCK = (n + BSZ - 1) >> BSH;
    const int subcap = ((E / (NBUCK * NSUB)) * 3 / 2 + 256 + 63) & ~63;

    char* p = (char*)d_ws;
    auto alloc = [&](size_t bytes) -> char* {
        char* r = p;
        p += (bytes + 511) & ~((size_t)511);
        return r;
    };
    u16*    xl      = (u16*)alloc((size_t)n * 256 * 2);
    u16*    xr      = (u16*)alloc((size_t)n * 256 * 2);
    float*  ybuf    = (float*)alloc((size_t)n * 64 * 4);
    int*    rowptr  = (int*)alloc((size_t)(n + 1) * 4);
    int*    cnt     = (int*)alloc((size_t)n * 4);
    const int nb    = (n + 255) / 256;
    int*    bsum    = (int*)alloc((size_t)nb * 4);
    int*    boff    = (int*)alloc((size_t)nb * 4);
    int*    col_src = (int*)alloc((size_t)(E + n + 8) * 4);
    int*    bcur    = (int*)alloc((size_t)NBUCK * NSUB * 16 * 4);
    u32*    stage   = (u32*)alloc((size_t)NBUCK * NSUB * subcap * 4);
    u16*    wt      = (u16*)alloc((size_t)6 * 16384 * 2);
    float*  buckets = (float*)alloc(1024 * 4);
    float*  musig   = (float*)alloc(16);

    // ---- bucketed CSR build (by dst, self loop first per node) ----
    k_init<<<(n + 255) / 256, 256, 0, stream>>>(bcur, NBUCK * NSUB * 16, buckets,
                                                col_src, E + n);
    k_bucketA<<<2048, 256, 0, stream>>>(srcA, dstA, bcur, stage, E, subcap);
    k_bcount<<<NBUCK, 256, 0, stream>>>(bcur, stage, cnt, n, subcap);
    k_blocksum<<<nb, 256, 0, stream>>>(cnt, bsum, n);
    k_scan_bsum<<<1, 1024, 0, stream>>>(bsum, boff, nb);
    k_make_ptr<<<nb, 256, 0, stream>>>(cnt, boff, rowptr, n);
    k_bfill<<<NBUCK, 256, 0, stream>>>(bcur, stage, rowptr, col_src, n, subcap);
    k_prep_w<<<(6 * 16384 + 255) / 256, 256, 0, stream>>>(Wl, Wr, wt);

    // ---- 3 GATv2 layers; LN affine fused into next layer's GEMM staging ----
    for (int l = 0; l < 3; ++l) {
        const float* xin = (l == 0) ? x0 : ybuf;
        k_gemm_mfma<<<(n + 255) / 256, 256, 0, stream>>>(
            xin, wt + (size_t)l * 16384, wt + (size_t)(3 + l) * 16384, xl, xr, n,
            musig, lnw + (l - 1) * 64, lnb + (l - 1) * 64, l > 0 ? 1 : 0);
        k_fused<<<(n + 3) / 4, 256, 0, stream>>>(
            xl, xr, rowptr, col_src, att + l * 256, bias + l * 64,
            ybuf, buckets, n);
        k_ln_final<<<1, 512, 0, stream>>>(buckets, musig, n * 64);
    }
    k_ln_apply<<<2048, 256, 0, stream>>>(ybuf, musig, lnw + 2 * 64, lnb + 2 * 64,
                                         (float*)d_out, n * 64);
}

// Round 14
// 653.577 us; speedup vs baseline: 1.0399x; 1.0399x over previous
//
#include <hip/hip_runtime.h>
#include <hip/hip_bf16.h>

#define HEADS 4
#define NEG 0.2f
#define LN_EPS 1e-5f
#define LOG2E 1.4426950408889634f

typedef unsigned int u32;
typedef unsigned short u16;

typedef __attribute__((ext_vector_type(8))) short bf16x8;
typedef __attribute__((ext_vector_type(4))) float f32x4;

__device__ __forceinline__ float bflo(u32 u) { return __uint_as_float(u << 16); }
__device__ __forceinline__ float bfhi(u32 u) { return __uint_as_float(u & 0xffff0000u); }
__device__ __forceinline__ u16 f2bf(float f) {
    u32 u = __float_as_uint(f);
    u32 r = u + 0x7fffu + ((u >> 16) & 1u);
    return (u16)(r >> 16);
}

template <int CTRL>
__device__ __forceinline__ float dppadd(float e) {
    float t = __int_as_float(
        __builtin_amdgcn_update_dpp(0, __float_as_int(e), CTRL, 0xf, 0xf, false));
    return e + t;
}
// sum over each 8-lane group
__device__ __forceinline__ float redsum8(float e) {
    e = dppadd<0xB1>(e);   // quad_perm [1,0,3,2]
    e = dppadd<0x4E>(e);   // quad_perm [2,3,0,1]
    e = dppadd<0x141>(e);  // row_half_mirror
    return e;
}

#define BSH 9
#define BSZ 512
#define NSUB 16

// ---------------- CSR build (XCD-affine substreamed buckets) ----------------
__global__ void k_init(int* bcur, int ncur, float* buckets) {
    int i = blockIdx.x * blockDim.x + threadIdx.x;
    if (i < ncur) bcur[i] = 0;
    if (i < 1024) buckets[i] = 0.f;
}

// partition edges into dst-buckets; substream = blockIdx&15 (XCD-affine pairs).
// Record packed: src | dstLocal<<20  (requires n < 2^20).
__global__ void k_bucketA(const int* __restrict__ src, const int* __restrict__ dst,
                          int* __restrict__ bcur, u32* __restrict__ stage,
                          int E, int subcap) {
    int sub = blockIdx.x & (NSUB - 1);
    int stride = gridDim.x * blockDim.x;
    for (int e = blockIdx.x * blockDim.x + threadIdx.x; e < E; e += stride) {
        int s = src[e], d = dst[e];
        int b = d >> BSH;
        int st = b * NSUB + sub;
        int pos = atomicAdd(&bcur[st * 16], 1);
        if (pos < subcap)
            stage[(size_t)st * subcap + pos] = (u32)s | ((u32)(d & (BSZ - 1)) << 20);
    }
}

// per-bucket LDS histogram -> per-node counts (incl. self loop)
__global__ void k_bcount(const int* __restrict__ bcur, const u32* __restrict__ stage,
                         int* __restrict__ cnt, int n, int subcap) {
    __shared__ int hist[BSZ];
    int b = blockIdx.x;
    int base = b << BSH;
    for (int i = threadIdx.x; i < BSZ; i += 256) hist[i] = 1;  // self loop
    __syncthreads();
    for (int ss = 0; ss < NSUB; ++ss) {
        int st = b * NSUB + ss;
        int c = min(bcur[st * 16], subcap);
        const u32* sp = stage + (size_t)st * subcap;
        for (int i = threadIdx.x; i < c; i += 256)
            atomicAdd(&hist[(sp[i] >> 20) & (BSZ - 1)], 1);
    }
    __syncthreads();
    for (int i = threadIdx.x; i < BSZ; i += 256)
        if (base + i < n) cnt[base + i] = hist[i];
}

__global__ void k_blocksum(const int* __restrict__ cnt, int* bsum, int n) {
    __shared__ int sh[256];
    int i = blockIdx.x * 256 + threadIdx.x;
    int v = (i < n) ? cnt[i] : 0;
    sh[threadIdx.x] = v;
    __syncthreads();
    for (int off = 128; off; off >>= 1) {
        if (threadIdx.x < off) sh[threadIdx.x] += sh[threadIdx.x + off];
        __syncthreads();
    }
    if (threadIdx.x == 0) bsum[blockIdx.x] = sh[0];
}

__global__ void k_scan_bsum(const int* __restrict__ bsum, int* boff, int nb) {
    __shared__ int sh[1024];
    int t = threadIdx.x;
    int v = (t < nb) ? bsum[t] : 0;
    sh[t] = v;
    __syncthreads();
    for (int off = 1; off < 1024; off <<= 1) {
        int a = (t >= off) ? sh[t - off] : 0;
        __syncthreads();
        sh[t] += a;
        __syncthreads();
    }
    if (t < nb) boff[t] = sh[t] - v;  // exclusive
}

__global__ void k_make_ptr(const int* cnt, const int* __restrict__ boff,
                           int* rowptr, int n) {
    __shared__ int sh[256];
    int t = threadIdx.x;
    int i = blockIdx.x * 256 + t;
    int v = (i < n) ? cnt[i] : 0;
    sh[t] = v;
    __syncthreads();
    for (int off = 1; off < 256; off <<= 1) {
        int a = (t >= off) ? sh[t - off] : 0;
        __syncthreads();
        sh[t] += a;
        __syncthreads();
    }
    int incl = sh[t] + boff[blockIdx.x];
    if (i < n) rowptr[i + 1] = incl;
    if (i == 0) rowptr[0] = 0;
}

// per-bucket scatter via LDS cursors
__global__ void k_bfill(const int* __restrict__ bcur, const u32* __restrict__ stage,
                        const int* __restrict__ rowptr, int* __restrict__ col_src,
                        int n, int subcap) {
    __shared__ int lcur[BSZ];
    int b = blockIdx.x;
    int base = b << BSH;
    for (int i = threadIdx.x; i < BSZ; i += 256) {
        if (base + i < n) {
            int rp = rowptr[base + i];
            col_src[rp] = base + i;  // self loop first (order only affects fp rounding)
            lcur[i] = rp + 1;
        }
    }
    __syncthreads();
    for (int ss = 0; ss < NSUB; ++ss) {
        int st = b * NSUB + ss;
        int c = min(bcur[st * 16], subcap);
        const u32* sp = stage + (size_t)st * subcap;
        for (int i = threadIdx.x; i < c; i += 256) {
            u32 rec = sp[i];
            int p = atomicAdd(&lcur[(rec >> 20) & (BSZ - 1)], 1);
            col_src[p] = (int)(rec & 0xFFFFFu);
        }
    }
}

// ---------------- W -> bf16 MFMA-fragment layout ----------------
__global__ void k_prep_w(const float* __restrict__ Wl, const float* __restrict__ Wr,
                         u16* __restrict__ wt) {
    int idx = blockIdx.x * 256 + threadIdx.x;
    if (idx >= 6 * 16384) return;
    int mat = idx >> 14;
    int rem = idx & 16383;
    int t = rem >> 10;
    int kq = (rem >> 8) & 3;
    int nn = (rem >> 4) & 15;
    int half = (rem >> 3) & 1;
    int j = rem & 7;
    int c = t * 16 + nn;
    int k = kq * 8 + half * 32 + j;
    const float* W = (mat < 3) ? (Wl + (size_t)mat * 16384) : (Wr + (size_t)(mat - 3) * 16384);
    wt[idx] = f2bf(W[k * 256 + c]);
}

// ---------------- MFMA GEMM, 256 rows/block: amortizes wt fragment reads 4x ----------------
__global__ __launch_bounds__(256) void k_gemm_mfma(
        const float* __restrict__ x, const u16* __restrict__ wtl,
        const u16* __restrict__ wtr, u16* __restrict__ xl, u16* __restrict__ xr, int n,
        const float* __restrict__ musig, const float* __restrict__ lnw,
        const float* __restrict__ lnb, int useln) {
    int w = threadIdx.x >> 6;
    int lane = threadIdx.x & 63;
    int rbase = blockIdx.x * 256 + w * 64;
    int rloc = lane & 15;
    int c0 = (lane >> 4) * 8;

    float mu = 0.f, rs = 1.f;
    if (useln) { mu = musig[0]; rs = musig[1]; }

    bf16x8 fa0[4], fa1[4];
#pragma unroll
    for (int g = 0; g < 4; ++g) {
        int r = rbase + g * 16 + rloc;
        float av[16];
        if (r < n) {
            const float* xp = x + (size_t)r * 64;
            float4 t0 = *(const float4*)(xp + c0);
            float4 t1 = *(const float4*)(xp + c0 + 4);
            float4 t2 = *(const float4*)(xp + c0 + 32);
            float4 t3 = *(const float4*)(xp + c0 + 36);
            av[0] = t0.x; av[1] = t0.y; av[2] = t0.z; av[3] = t0.w;
            av[4] = t1.x; av[5] = t1.y; av[6] = t1.z; av[7] = t1.w;
            av[8] = t2.x; av[9] = t2.y; av[10] = t2.z; av[11] = t2.w;
            av[12] = t3.x; av[13] = t3.y; av[14] = t3.z; av[15] = t3.w;
            if (useln) {
                float4 w0 = *(const float4*)(lnw + c0);
                float4 w1 = *(const float4*)(lnw + c0 + 4);
                float4 w2 = *(const float4*)(lnw + c0 + 32);
                float4 w3 = *(const float4*)(lnw + c0 + 36);
                float4 b0 = *(const float4*)(lnb + c0);
                float4 b1 = *(const float4*)(lnb + c0 + 4);
                float4 b2 = *(const float4*)(lnb + c0 + 32);
                float4 b3 = *(const float4*)(lnb + c0 + 36);
                float lw[16] = {w0.x,w0.y,w0.z,w0.w, w1.x,w1.y,w1.z,w1.w,
                                w2.x,w2.y,w2.z,w2.w, w3.x,w3.y,w3.z,w3.w};
                float lb[16] = {b0.x,b0.y,b0.z,b0.w, b1.x,b1.y,b1.z,b1.w,
                                b2.x,b2.y,b2.z,b2.w, b3.x,b3.y,b3.z,b3.w};
#pragma unroll
                for (int j = 0; j < 16; ++j) av[j] = (av[j] - mu) * rs * lw[j] + lb[j];
            }
        } else {
#pragma unroll
            for (int j = 0; j < 16; ++j) av[j] = 0.f;
        }
#pragma unroll
        for (int j = 0; j < 8; ++j) {
            fa0[g][j] = (short)f2bf(av[j]);
            fa1[g][j] = (short)f2bf(av[8 + j]);
        }
    }

    int nn = lane & 15;
    int kq = lane >> 4;
    int fragoff = kq * 256 + nn * 16;

#pragma unroll 2
    for (int t = 0; t < 16; ++t) {
        const u16* wp = wtl + t * 1024 + fragoff;
        bf16x8 fb0 = *(const bf16x8*)(wp);
        bf16x8 fb1 = *(const bf16x8*)(wp + 8);
        int cb = t * 16;
#pragma unroll
        for (int g = 0; g < 4; ++g) {
            f32x4 acc = {0.f, 0.f, 0.f, 0.f};
            acc = __builtin_amdgcn_mfma_f32_16x16x32_bf16(fa0[g], fb0, acc, 0, 0, 0);
            acc = __builtin_amdgcn_mfma_f32_16x16x32_bf16(fa1[g], fb1, acc, 0, 0, 0);
            int row0 = rbase + g * 16 + kq * 4;
#pragma unroll
            for (int reg = 0; reg < 4; ++reg) {
                int R = row0 + reg;
                if (R < n) xl[(size_t)R * 256 + cb + nn] = f2bf(acc[reg]);
            }
        }
    }
#pragma unroll 2
    for (int t = 0; t < 16; ++t) {
        const u16* wp = wtr + t * 1024 + fragoff;
        bf16x8 fb0 = *(const bf16x8*)(wp);
        bf16x8 fb1 = *(const bf16x8*)(wp + 8);
        int cb = t * 16;
#pragma unroll
        for (int g = 0; g < 4; ++g) {
            f32x4 acc = {0.f, 0.f, 0.f, 0.f};
            acc = __builtin_amdgcn_mfma_f32_16x16x32_bf16(fa0[g], fb0, acc, 0, 0, 0);
            acc = __builtin_amdgcn_mfma_f32_16x16x32_bf16(fa1[g], fb1, acc, 0, 0, 0);
            int row0 = rbase + g * 16 + kq * 4;
#pragma unroll
            for (int reg = 0; reg < 4; ++reg) {
                int R = row0 + reg;
                if (R < n) xr[(size_t)R * 256 + cb + nn] = f2bf(acc[reg]);
            }
        }
    }
}

// ---------------- Fused GATv2 edge pass (r6/r12 form: minimal registers) ----------------
// Wave per dst node; half = lane>>5 (edge stream), l32 = lane&31, 8 ch/lane,
// head = l32>>3. Two edges per iteration, 3-step DPP logit reduce, att
// pre-scaled by log2e so p = exp2(e). Fused LN stats via bucketed atomics.
__global__ __launch_bounds__(256) void k_fused(
        const u16* __restrict__ xl, const u16* __restrict__ xr,
        const int* __restrict__ rowptr, const int* __restrict__ col_src,
        const float* __restrict__ att, const float* __restrict__ bias,
        float* __restrict__ y, float* __restrict__ buckets, int n) {
    __shared__ float shv[4][HEADS][64];
    __shared__ float redS[4], redQ[4];
    int w = threadIdx.x >> 6;
    int node = blockIdx.x * 4 + w;
    int lane = threadIdx.x & 63;
    int half = lane >> 5;
    int l32 = lane & 31;
    bool act = node < n;
    float yv = 0.f;

    if (act) {
        float a[8], rr[8];
        {
            const float* ap = att + l32 * 8;
            float4 a0 = *(const float4*)(ap);
            float4 a1 = *(const float4*)(ap + 4);
            a[0] = a0.x * LOG2E; a[1] = a0.y * LOG2E; a[2] = a0.z * LOG2E; a[3] = a0.w * LOG2E;
            a[4] = a1.x * LOG2E; a[5] = a1.y * LOG2E; a[6] = a1.z * LOG2E; a[7] = a1.w * LOG2E;
            uint4 rv = *(const uint4*)(xr + (size_t)node * 256 + l32 * 8);
            rr[0] = bflo(rv.x); rr[1] = bfhi(rv.x);
            rr[2] = bflo(rv.y); rr[3] = bfhi(rv.y);
            rr[4] = bflo(rv.z); rr[5] = bfhi(rv.z);
            rr[6] = bflo(rv.w); rr[7] = bfhi(rv.w);
        }
        int start = rowptr[node], end = rowptr[node + 1];
        int d = end - start;
        int iters = (d + 1) >> 1;
        float acc[8] = {0.f, 0.f, 0.f, 0.f, 0.f, 0.f, 0.f, 0.f};
        float denom = 0.f;
        int j = start + half;
        const size_t co = (size_t)l32 * 8;
        uint4 v;
        {
            int jc = min(j, end - 1);
            int s = col_src[jc];
            v = *(const uint4*)(xl + (size_t)s * 256 + co);
        }
        for (int i = 0; i < iters; ++i) {
            uint4 vc = v;
            bool valid = j < end;
            int jn = j + 2;
            if (i + 1 < iters) {
                int jnc = min(jn, end - 1);
                int sn = col_src[jnc];
                v = *(const uint4*)(xl + (size_t)sn * 256 + co);
            }
            float x0 = bflo(vc.x), x1 = bfhi(vc.x), x2 = bflo(vc.y), x3 = bfhi(vc.y);
            float x4 = bflo(vc.z), x5 = bfhi(vc.z), x6 = bflo(vc.w), x7 = bfhi(vc.w);
            float e0 = x0 + rr[0], e1 = x1 + rr[1], e2 = x2 + rr[2], e3 = x3 + rr[3];
            float e4 = x4 + rr[4], e5 = x5 + rr[5], e6 = x6 + rr[6], e7 = x7 + rr[7];
            e0 = fmaxf(e0, NEG * e0); e1 = fmaxf(e1, NEG * e1);
            e2 = fmaxf(e2, NEG * e2); e3 = fmaxf(e3, NEG * e3);
            e4 = fmaxf(e4, NEG * e4); e5 = fmaxf(e5, NEG * e5);
            e6 = fmaxf(e6, NEG * e6); e7 = fmaxf(e7, NEG * e7);
            float e = a[0] * e0;
            e = fmaf(a[1], e1, e);
            e = fmaf(a[2], e2, e);
            e = fmaf(a[3], e3, e);
            e = fmaf(a[4], e4, e);
            e = fmaf(a[5], e5, e);
            e = fmaf(a[6], e6, e);
            e = fmaf(a[7], e7, e);
            e = redsum8(e);
            float p = exp2f(e);
            p = valid ? p : 0.f;
            denom += p;
            acc[0] = fmaf(p, x0, acc[0]);
            acc[1] = fmaf(p, x1, acc[1]);
            acc[2] = fmaf(p, x2, acc[2]);
            acc[3] = fmaf(p, x3, acc[3]);
            acc[4] = fmaf(p, x4, acc[4]);
            acc[5] = fmaf(p, x5, acc[5]);
            acc[6] = fmaf(p, x6, acc[6]);
            acc[7] = fmaf(p, x7, acc[7]);
            j = jn;
        }
        // fold the two edge streams
#pragma unroll
        for (int q = 0; q < 8; ++q) acc[q] += __shfl_xor(acc[q], 32, 64);
        denom += __shfl_xor(denom, 32, 64);
        float invd = 0.25f / (denom + 1e-16f);
        if (half == 0) {
            int h = l32 >> 3;
            int cb = (l32 & 7) * 8;
#pragma unroll
            for (int q = 0; q < 8; ++q) shv[w][h][cb + q] = acc[q] * invd;
        }
        // same-wave DS write->read: in-order, no barrier needed
        yv = shv[w][0][lane] + shv[w][1][lane] + shv[w][2][lane] + shv[w][3][lane]
             + bias[lane];
        y[(size_t)node * 64 + lane] = yv;
    }

    // fused LN statistics
    float s1 = yv, s2 = yv * yv;
#pragma unroll
    for (int off = 32; off; off >>= 1) {
        s1 += __shfl_xor(s1, off, 64);
        s2 += __shfl_xor(s2, off, 64);
    }
    if (lane == 0) { redS[w] = act ? s1 : 0.f; redQ[w] = act ? s2 : 0.f; }
    __syncthreads();
    if (threadIdx.x == 0) {
        float bs = redS[0] + redS[1] + redS[2] + redS[3];
        float bq = redQ[0] + redQ[1] + redQ[2] + redQ[3];
        int b = blockIdx.x & 511;
        atomicAdd(&buckets[b], bs);
        atomicAdd(&buckets[512 + b], bq);
    }
}

// ---------------- LayerNorm finalize ----------------
__global__ void k_ln_final(float* __restrict__ buckets, float* musig, int n64) {
    int t = threadIdx.x;  // 512
    double s = (double)buckets[t];
    double q = (double)buckets[512 + t];
    __shared__ double shs[512], shq[512];
    shs[t] = s; shq[t] = q;
    __syncthreads();
    for (int off = 256; off; off >>= 1) {
        if (t < off) { shs[t] += shs[t + off]; shq[t] += shq[t + off]; }
        __syncthreads();
    }
    if (t == 0) {
        double mu = shs[0] / n64;
        double var = shq[0] / n64 - mu * mu;
        musig[0] = (float)mu;
        musig[1] = (float)(1.0 / sqrt(var + (double)LN_EPS));
    }
    buckets[t] = 0.f;
    buckets[512 + t] = 0.f;
}

__global__ void k_ln_apply(const float* __restrict__ y, const float* __restrict__ musig,
                           const float* __restrict__ w, const float* __restrict__ b,
                           float* __restrict__ out, int n64) {
    float mu = musig[0], rs = musig[1];
    int stride = gridDim.x * blockDim.x;
    for (int i = blockIdx.x * blockDim.x + threadIdx.x; i < n64; i += stride) {
        int c = i & 63;
        out[i] = (y[i] - mu) * rs * w[c] + b[c];
    }
}

extern "C" void kernel_launch(void* const* d_in, const int* in_sizes, int n_in,
                              void* d_out, int out_size, void* d_ws, size_t ws_size,
                              hipStream_t stream) {
    const float* x0   = (const float*)d_in[0];
    const int*   ei   = (const int*)d_in[1];
    const float* Wl   = (const float*)d_in[2];
    const float* Wr   = (const float*)d_in[3];
    const float* att  = (const float*)d_in[4];
    const float* bias = (const float*)d_in[5];
    const float* lnw  = (const float*)d_in[6];
    const float* lnb  = (const float*)d_in[7];

    const int n  = in_sizes[0] / 64;
    const int E  = in_sizes[1] / 2;
    const int* srcA = ei;
    const int* dstA = ei + E;

    const int NBUCK = (n + BSZ - 1) >> BSH;
    const int subcap = ((E / (NBUCK * NSUB)) * 3 / 2 + 256 + 63) & ~63;

    char* p = (char*)d_ws;
    auto alloc = [&](size_t bytes) -> char* {
        char* r = p;
        p += (bytes + 511) & ~((size_t)511);
        return r;
    };
    u16*    xl      = (u16*)alloc((size_t)n * 256 * 2);
    u16*    xr      = (u16*)alloc((size_t)n * 256 * 2);
    float*  ybuf    = (float*)alloc((size_t)n * 64 * 4);
    int*    rowptr  = (int*)alloc((size_t)(n + 1) * 4);
    int*    cnt     = (int*)alloc((size_t)n * 4);
    const int nb    = (n + 255) / 256;
    int*    bsum    = (int*)alloc((size_t)nb * 4);
    int*    boff    = (int*)alloc((size_t)nb * 4);
    int*    col_src = (int*)alloc((size_t)(E + n) * 4);
    int*    bcur    = (int*)alloc((size_t)NBUCK * NSUB * 16 * 4);
    u32*    stage   = (u32*)alloc((size_t)NBUCK * NSUB * subcap * 4);
    u16*    wt      = (u16*)alloc((size_t)6 * 16384 * 2);
    float*  buckets = (float*)alloc(1024 * 4);
    float*  musig   = (float*)alloc(16);

    // ---- bucketed CSR build (by dst, self loop first per node) ----
    k_init<<<(n + 255) / 256, 256, 0, stream>>>(bcur, NBUCK * NSUB * 16, buckets);
    k_bucketA<<<2048, 256, 0, stream>>>(srcA, dstA, bcur, stage, E, subcap);
    k_bcount<<<NBUCK, 256, 0, stream>>>(bcur, stage, cnt, n, subcap);
    k_blocksum<<<nb, 256, 0, stream>>>(cnt, bsum, n);
    k_scan_bsum<<<1, 1024, 0, stream>>>(bsum, boff, nb);
    k_make_ptr<<<nb, 256, 0, stream>>>(cnt, boff, rowptr, n);
    k_bfill<<<NBUCK, 256, 0, stream>>>(bcur, stage, rowptr, col_src, n, subcap);
    k_prep_w<<<(6 * 16384 + 255) / 256, 256, 0, stream>>>(Wl, Wr, wt);

    // ---- 3 GATv2 layers; LN affine fused into next layer's GEMM staging ----
    for (int l = 0; l < 3; ++l) {
        const float* xin = (l == 0) ? x0 : ybuf;
        k_gemm_mfma<<<(n + 255) / 256, 256, 0, stream>>>(
            xin, wt + (size_t)l * 16384, wt + (size_t)(3 + l) * 16384, xl, xr, n,
            musig, lnw + (l - 1) * 64, lnb + (l - 1) * 64, l > 0 ? 1 : 0);
        k_fused<<<(n + 3) / 4, 256, 0, stream>>>(
            xl, xr, rowptr, col_src, att + l * 256, bias + l * 64,
            ybuf, buckets, n);
        k_ln_final<<<1, 512, 0, stream>>>(buckets, musig, n * 64);
    }
    k_ln_apply<<<2048, 256, 0, stream>>>(ybuf, musig, lnw + 2 * 64, lnb + 2 * 64,
                                         (float*)d_out, n * 64);
}